// Round 10
// baseline (6594.762 us; speedup 1.0000x reference)
//
#include <hip/hip_runtime.h>
#include <stdint.h>

#define DI __device__ __forceinline__

static constexpr int B   = 4;
static constexpr int N   = 8192;
static constexpr int M   = 2048;
static constexpr int KNN = 16;
static constexpr int O   = 64;
static constexpr int E   = 65;   // 2C+1 edge channels
static constexpr int NG  = 128;  // FPS groups per batch (64 pts each)

typedef float f32x2 __attribute__((ext_vector_type(2)));

DI float fadd(float a, float b){ return __fadd_rn(a,b); }
DI float fsub(float a, float b){ return __fsub_rn(a,b); }
DI float fmul(float a, float b){ return __fmul_rn(a,b); }

#if __has_builtin(__builtin_elementwise_fma)
DI f32x2 efma(f32x2 a, f32x2 b, f32x2 c){ return __builtin_elementwise_fma(a,b,c); }
#else
DI f32x2 efma(f32x2 a, f32x2 b, f32x2 c){ return (f32x2){fmaf(a.x,b.x,c.x), fmaf(a.y,b.y,c.y)}; }
#endif

// one DPP max step: t = max(t, dpp_perm(t))  (invalid source -> 0, fine for >=0 data)
template<int CTRL>
DI float dppmax(float v){
  int t = __builtin_amdgcn_update_dpp(0, __float_as_int(v), CTRL, 0xf, 0xf, true);
  return fmaxf(v, __int_as_float(t));
}
DI float wave_max_bcast63(float v){
  v = dppmax<0xB1>(v);   // quad_perm xor1
  v = dppmax<0x4E>(v);   // quad_perm xor2
  v = dppmax<0x141>(v);  // row_half_mirror
  v = dppmax<0x140>(v);  // row_mirror
  v = dppmax<0x142>(v);  // row_bcast15
  v = dppmax<0x143>(v);  // row_bcast31 -> full max in lane 63
  return __int_as_float(__builtin_amdgcn_readlane(__float_as_int(v), 63));
}
// int min-reduce: invalid source keeps OWN value (old=v, bound_ctrl=false) so min unaffected
template<int CTRL>
DI int dppmin_i(int v){
  int t = __builtin_amdgcn_update_dpp(v, v, CTRL, 0xf, 0xf, false);
  return t < v ? t : v;
}
DI int wave_min_bcast63_i(int v){
  v = dppmin_i<0xB1>(v);
  v = dppmin_i<0x4E>(v);
  v = dppmin_i<0x141>(v);
  v = dppmin_i<0x140>(v);
  v = dppmin_i<0x142>(v);
  v = dppmin_i<0x143>(v);
  return __builtin_amdgcn_readlane(v, 63);
}

DI unsigned mort1(unsigned x){   // spread 4 bits to every 3rd position
  return (x & 1u) | ((x & 2u) << 2) | ((x & 4u) << 4) | ((x & 8u) << 6);
}

// ---------------- K0a: feat (B,96,N) -> featT (B,N,96) ----------------
__global__ __launch_bounds__(256) void k_transpose(const float* __restrict__ feat,
                                                   float* __restrict__ featT){
  __shared__ float tile[64*97];
  int blk = blockIdx.x;
  int b = blk / (N/64);
  int n0 = (blk % (N/64)) * 64;
  const float* fb = feat + (size_t)b*96*N;
  for (int e = threadIdx.x; e < 96*64; e += 256){
    int cv = e >> 6, nn = e & 63;
    tile[nn*97 + cv] = fb[(size_t)cv*N + n0 + nn];
  }
  __syncthreads();
  float* ob = featT + ((size_t)b*N + n0)*96;
  for (int e = threadIdx.x; e < 96*64; e += 256){
    int nn = e / 96, cv = e - nn*96;
    ob[e] = tile[nn*97 + cv];
  }
}

// ---------------- K0b: xyz -> SoA + per-point squared norms ----------------
__global__ __launch_bounds__(256) void k_xyz_pre(const float* __restrict__ xyz,
                                                 float* __restrict__ xsoa,
                                                 float* __restrict__ sx){
  int i = blockIdx.x*256 + threadIdx.x;
  if (i >= B*N) return;
  int b = i >> 13, n = i & 8191;
  float x = xyz[(size_t)i*3+0], y = xyz[(size_t)i*3+1], z = xyz[(size_t)i*3+2];
  xsoa[((size_t)b*3+0)*N + n] = x;
  xsoa[((size_t)b*3+1)*N + n] = y;
  xsoa[((size_t)b*3+2)*N + n] = z;
  sx[i] = fadd(fadd(fmul(x,x),fmul(y,y)),fmul(z,z));   // numpy order ((x2+y2)+z2)
}

// ---------------- K1a: Morton counting-sort (per batch) ----------------
// Within-cell order nondeterministic (LDS atomics) — harmless: with exact
// min-original-index tie-breaking in k_fps, results are order-independent.
__global__ __launch_bounds__(256) void k_sort(const float* __restrict__ xsoa,
                                              float* __restrict__ slx, float* __restrict__ sly,
                                              float* __restrict__ slz,
                                              unsigned short* __restrict__ sidx){
  int b = blockIdx.x, tid = threadIdx.x;
  const float* X = xsoa + (size_t)b*3*N;
  __shared__ unsigned hist[4096];
  __shared__ unsigned basep[4096];
  __shared__ unsigned tot[256];
  for (int i = tid; i < 4096; i += 256) hist[i] = 0;
  __syncthreads();
  unsigned short cell[32];
  #pragma unroll 4
  for (int j = 0; j < 32; ++j){
    int n = tid*32 + j;
    float x = X[n], y = X[N+n], z = X[2*N+n];
    int ix = (int)floorf((x + 6.f) * (4.f/3.f)); ix = ix < 0 ? 0 : (ix > 15 ? 15 : ix);
    int iy = (int)floorf((y + 6.f) * (4.f/3.f)); iy = iy < 0 ? 0 : (iy > 15 ? 15 : iy);
    int iz = (int)floorf((z + 6.f) * (4.f/3.f)); iz = iz < 0 ? 0 : (iz > 15 ? 15 : iz);
    unsigned c = mort1((unsigned)ix) | (mort1((unsigned)iy) << 1) | (mort1((unsigned)iz) << 2);
    cell[j] = (unsigned short)c;
    atomicAdd(&hist[c], 1u);
  }
  __syncthreads();
  unsigned run = 0;
  for (int i = 0; i < 16; ++i){ unsigned h = hist[tid*16+i]; basep[tid*16+i] = run; run += h; }
  tot[tid] = run;
  __syncthreads();
  for (int off = 1; off < 256; off <<= 1){
    unsigned add = (tid >= off) ? tot[tid-off] : 0u;
    __syncthreads();
    tot[tid] += add;
    __syncthreads();
  }
  unsigned cb = (tid == 0) ? 0u : tot[tid-1];
  for (int i = 0; i < 16; ++i) basep[tid*16+i] += cb;
  __syncthreads();
  for (int i = tid; i < 4096; i += 256) hist[i] = 0;
  __syncthreads();
  #pragma unroll 4
  for (int j = 0; j < 32; ++j){
    int n = tid*32 + j;
    unsigned c = cell[j];
    unsigned pos = basep[c] + atomicAdd(&hist[c], 1u);
    slx[(size_t)b*N + pos] = X[n];
    sly[(size_t)b*N + pos] = X[N+n];
    slz[(size_t)b*N + pos] = X[2*N+n];
    sidx[(size_t)b*N + pos] = (unsigned short)n;
  }
}

// ---------------- K1b: per-group centroid + conservative radius ----------------
__global__ __launch_bounds__(64) void k_gstat(const float* __restrict__ slx,
                                              const float* __restrict__ sly,
                                              const float* __restrict__ slz,
                                              float4* __restrict__ gstat){
  int g = blockIdx.x;              // 0 .. B*NG-1
  int tid = threadIdx.x;
  size_t j = (size_t)g*64 + tid;
  float x = slx[j], y = sly[j], z = slz[j];
  float sxv = x, syv = y, szv = z;
  #pragma unroll
  for (int s = 1; s < 64; s <<= 1){
    sxv += __shfl_xor(sxv, s, 64); syv += __shfl_xor(syv, s, 64); szv += __shfl_xor(szv, s, 64);
  }
  float cx = sxv*(1.f/64.f), cy = syv*(1.f/64.f), cz = szv*(1.f/64.f);
  float dx = x-cx, dy = y-cy, dz = z-cz;
  float d = sqrtf(dx*dx + dy*dy + dz*dz);
  #pragma unroll
  for (int s = 1; s < 64; s <<= 1) d = fmaxf(d, __shfl_xor(d, s, 64));
  if (tid == 0) gstat[g] = make_float4(cx, cy, cz, fmaf(d, 1.0001f, 1e-7f));  // radius rounded UP
}

// ---------------- K1c: pruned farthest point sampling (exact, tie-exact) ----------------
// Pruning: group g skipped iff (0.99999*||gc-c||-r)^2*0.9999 > gmax[g] — conservative
// margins (1e-4 >> fp32 eps) guarantee min(dist,d)=dist bit-exactly for skipped pts.
// Tie-break now EXACT numpy first-occurrence: among all points achieving the exact
// max value, the SMALLEST ORIGINAL INDEX wins (DPP int-min over keyed sidxl within
// tied groups; (value desc, idx asc) order across groups and waves). Results are
// therefore independent of the sort's within-cell nondeterminism.
__global__ __launch_bounds__(256, 1) void k_fps(const float* __restrict__ xsoa,
                                                const float* __restrict__ slx,
                                                const float* __restrict__ sly,
                                                const float* __restrict__ slz,
                                                const unsigned short* __restrict__ sidx,
                                                const float4* __restrict__ gstat,
                                                int* __restrict__ fps_idx,
                                                float* __restrict__ newxyz){
  #pragma clang fp contract(off)
  int b = blockIdx.x, tid = threadIdx.x;
  int lane = tid & 63, wid = tid >> 6;
  __shared__ float lxl[N], lyl[N], lzl[N], dl[N];        // 128 KB
  __shared__ unsigned short sidxl[N];                    // 16 KB
  __shared__ __align__(16) float4 gst[NG];
  __shared__ float gmaxl[NG];
  __shared__ float4 pub[2][4];
  __shared__ unsigned pubi[2][4];

  const float* SXp = slx + (size_t)b*N;
  const float* SYp = sly + (size_t)b*N;
  const float* SZp = slz + (size_t)b*N;
  const unsigned short* SIp = sidx + (size_t)b*N;
  for (int j = tid; j < N; j += 256){
    lxl[j] = SXp[j]; lyl[j] = SYp[j]; lzl[j] = SZp[j];
    dl[j] = 1e10f; sidxl[j] = SIp[j];
  }
  if (tid < NG){ gst[tid] = gstat[b*NG + tid]; gmaxl[tid] = 1e10f; }

  const float* X = xsoa + (size_t)b*3*N;
  float cx = X[0], cy = X[N], cz = X[2*N];   // original index 0 = first centroid
  if (tid == 0){
    fps_idx[b*M] = 0;
    newxyz[(size_t)(b*M)*3+0] = cx;
    newxyz[(size_t)(b*M)*3+1] = cy;
    newxyz[(size_t)(b*M)*3+2] = cz;
  }
  __syncthreads();

  for (int it = 1; it < M; ++it){
    // ---- bound phase (lane-parallel over this wave's 32 groups)
    int g = (wid << 5) + (lane & 31);
    float4 gs = gst[g];
    float bdx = fsub(gs.x, cx), bdy = fsub(gs.y, cy), bdz = fsub(gs.z, cz);
    float D   = sqrtf(fadd(fadd(fmul(bdx,bdx), fmul(bdy,bdy)), fmul(bdz,bdz)));
    float lb  = fmaxf(fsub(fmul(D, 0.99999f), gs.w), 0.f);
    float lb2 = fmul(fmul(lb, lb), 0.9999f);
    bool act  = !(lb2 > gmaxl[g]);
    unsigned mask = (unsigned)(__ballot(act) & 0xFFFFFFFFull);   // low 32 = groups

    // ---- update phase (exact reference arithmetic, group <-> 64 lanes)
    while (mask){
      int gb = __ffs(mask) - 1; mask &= mask - 1;
      int gg = (wid << 5) + gb;
      int j  = (gg << 6) + lane;
      float ddx = fsub(lxl[j], cx), ddy = fsub(lyl[j], cy), ddz = fsub(lzl[j], cz);
      float d   = fadd(fadd(fmul(ddx,ddx), fmul(ddy,ddy)), fmul(ddz,ddz));
      float nd  = fminf(dl[j], d);
      dl[j] = nd;
      float gm_ = wave_max_bcast63(nd);     // exact new group max
      if (lane == 0) gmaxl[gg] = gm_;
    }

    // ---- wave winner value (max over own 32 group maxima)
    float gv = gmaxl[(wid << 5) + (lane & 31)];
    float wm = wave_max_bcast63(gv);

    // ---- tie-exact resolve: min ORIGINAL index among all pts with dl==wm (this wave)
    unsigned gm_mask = (unsigned)(__ballot(gv == wm) & 0xFFFFFFFFull);
    int bi = 0x7FFFFFFF, bs = 0;
    while (gm_mask){
      int gb = __ffs(gm_mask) - 1; gm_mask &= gm_mask - 1;
      int gg = (wid << 5) + gb;
      int j  = (gg << 6) + lane;
      int key = (dl[j] == wm) ? (int)sidxl[j] : 0x7FFFFFFF;
      int mi  = wave_min_bcast63_i(key);
      if (mi < bi){
        bi = mi;
        unsigned long long lm = __ballot(key == mi);
        bs = (gg << 6) + (__ffsll(lm) - 1);
      }
    }
    int buf = it & 1;
    if (lane == 0){
      pub[buf][wid]  = make_float4(lxl[bs], lyl[bs], lzl[bs], wm);
      pubi[buf][wid] = (unsigned)bi;
    }
    __syncthreads();

    // ---- global select: (value desc, original index asc) — exact numpy argmax
    float4  p0 = pub[buf][0], p1 = pub[buf][1], p2 = pub[buf][2], p3 = pub[buf][3];
    unsigned i0 = pubi[buf][0], i1 = pubi[buf][1], i2 = pubi[buf][2], i3 = pubi[buf][3];
    if (p1.w > p0.w || (p1.w == p0.w && i1 < i0)){ p0 = p1; i0 = i1; }
    if (p2.w > p0.w || (p2.w == p0.w && i2 < i0)){ p0 = p2; i0 = i2; }
    if (p3.w > p0.w || (p3.w == p0.w && i3 < i0)){ p0 = p3; i0 = i3; }
    cx = p0.x; cy = p0.y; cz = p0.z;
    if (tid == 0){
      fps_idx[b*M + it] = (int)i0;
      newxyz[(size_t)(b*M+it)*3+0] = cx;
      newxyz[(size_t)(b*M+it)*3+1] = cy;
      newxyz[(size_t)(b*M+it)*3+2] = cz;
    }
  }
}

// ---------------- K2: brute-force kNN (k=16), one wave per query ----------------
__global__ __launch_bounds__(256) void k_knn(const float* __restrict__ xsoa,
                                             const float* __restrict__ sx,
                                             const float* __restrict__ newxyz,
                                             int* __restrict__ gidx){
  __shared__ unsigned long long heap[4][64][17];
  __shared__ unsigned long long outk[4][16];
  int tid = threadIdx.x;
  int lane = tid & 63, wv = tid >> 6;
  int w = blockIdx.x*4 + wv;                 // query id, B*M total
  int b = w >> 11;
  const float* X  = xsoa + (size_t)b*3*N;
  const float* SX = sx   + (size_t)b*N;
  float qx = newxyz[(size_t)w*3+0], qy = newxyz[(size_t)w*3+1], qz = newxyz[(size_t)w*3+2];
  float sn = fadd(fadd(fmul(qx,qx),fmul(qy,qy)),fmul(qz,qz));

  unsigned long long cand[16];
  #pragma unroll
  for (int i = 0; i < 16; ++i) cand[i] = 0xFFFFFFFFFFFFFFFFull;

  for (int r = 0; r < 128; ++r){
    int n = (r << 6) + lane;
    float p0 = fmul(qx, X[n]), p1 = fmul(qy, X[N+n]), p2 = fmul(qz, X[2*N+n]);
    float dot = fadd(fadd(p0, p1), p2);
    float d2  = fsub(fadd(sn, SX[n]), fmul(2.0f, dot));   // reference expansion, matching op order
    unsigned u = __float_as_uint(d2);
    u ^= ((unsigned)((int)u >> 31)) | 0x80000000u;        // monotone f32->u32
    unsigned long long key = ((unsigned long long)u << 32) | (unsigned)n;
    if (key < cand[15]){
      #pragma unroll
      for (int i = 0; i < 16; ++i){                        // branch-free sorted insertion
        unsigned long long a = cand[i];
        bool sw = key < a;
        unsigned long long lo = sw ? key : a;
        unsigned long long hi = sw ? a : key;
        cand[i] = lo; key = hi;
      }
    }
  }
  #pragma unroll
  for (int i = 0; i < 16; ++i) heap[wv][lane][i] = cand[i];
  unsigned long long my = cand[0];
  int head = 0;
  for (int round = 0; round < 16; ++round){                // 16x extract-min across wave
    unsigned long long k = my;
    #pragma unroll
    for (int s = 1; s < 64; s <<= 1){
      unsigned long long o_ = __shfl_xor(k, s, 64);
      if (o_ < k) k = o_;
    }
    if (my == k){
      ++head;
      my = (head < 16) ? heap[wv][lane][head] : 0xFFFFFFFFFFFFFFFFull;
    }
    if (lane == 0) outk[wv][round] = k;
  }
  __syncthreads();
  if (lane < 16) gidx[(size_t)w*16 + lane] = (int)(unsigned)(outk[wv][lane] & 0xFFFFFFFFull);
}

// ---------------- K3/K5: edge conv, anchor-folded form ----------------
template<int PASSB>
__global__ __launch_bounds__(256) void k_conv(const float* __restrict__ featT,
                                              const float* __restrict__ xsoa,
                                              const float* __restrict__ newxyz,
                                              const int*   __restrict__ fps_idx,
                                              const int*   __restrict__ gidx,
                                              const float* __restrict__ Wf,
                                              const float* __restrict__ Wd,
                                              const float* __restrict__ bn_stats,  // mu[64], scale[64]
                                              const float* __restrict__ bn_bias,
                                              float* __restrict__ bn_part,
                                              float* __restrict__ nf){
  __shared__ float sW0[O*E];
  __shared__ float sW1[PASSB ? O*E : 1];
  __shared__ __align__(16) float sNG[99*20];   // rows 0..95: neigh cv; rows 96..98: rel v
  __shared__ float sA[96];
  __shared__ float red[3*256];

  int blk = blockIdx.x;                // b*M + m
  int b = blk >> 11, m = blk & 2047;
  int tid = threadIdx.x;

  for (int e = tid; e < O*E; e += 256) sW0[e] = Wf[e];
  if (PASSB){ for (int e = tid; e < O*E; e += 256) sW1[e] = Wd[e]; }
  int aidx = fps_idx[blk];
  if (tid < 96) sA[tid] = featT[((size_t)(b*N) + aidx)*96 + tid];

  #pragma unroll 4
  for (int kk = 0; kk < KNN; ++kk){
    int n = gidx[(size_t)blk*KNN + kk];
    if (tid < 96){
      sNG[tid*20 + kk] = featT[((size_t)(b*N) + n)*96 + tid];
    } else if (tid < 99){
      int v = tid - 96;
      sNG[(96+v)*20 + kk] = fsub(xsoa[((size_t)(b*3+v))*N + n], newxyz[(size_t)blk*3 + v]);
    }
  }
  __syncthreads();

  int o  = tid & 63;
  int w0 = tid >> 6;           // wave owns kk = 4*w0 + r, r=0..3

  float awf[3] = {0,0,0}, awd[3] = {0,0,0};
  for (int c = 0; c < 32; ++c){
    float df = sW0[o*E+32+c] - sW0[o*E+c];
    float dd = PASSB ? (sW1[o*E+32+c] - sW1[o*E+c]) : 0.f;
    #pragma unroll
    for (int v = 0; v < 3; ++v){
      float a = sA[c*3+v];
      awf[v] = fmaf(df, a, awf[v]);
      if (PASSB) awd[v] = fmaf(dd, a, awd[v]);
    }
  }

  float p[4][3], q[4][3];
  if (PASSB){
    f32x2 pA[2][3], qA[2][3];
    {
      float wr  = sW0[o*E+64];
      float wrd = sW1[o*E+64];
      f32x2 wr2  = (f32x2){wr, wr};
      f32x2 wrd2 = (f32x2){wrd, wrd};
      #pragma unroll
      for (int v = 0; v < 3; ++v){
        const float4 rv = *reinterpret_cast<const float4*>(&sNG[(96+v)*20 + 4*w0]);
        f32x2 r01 = (f32x2){rv.x, rv.y}, r23 = (f32x2){rv.z, rv.w};
        f32x2 awf2 = (f32x2){awf[v], awf[v]};
        f32x2 awd2 = (f32x2){awd[v], awd[v]};
        pA[0][v] = efma(wr2,  r01, awf2);  pA[1][v] = efma(wr2,  r23, awf2);
        qA[0][v] = efma(wrd2, r01, awd2);  qA[1][v] = efma(wrd2, r23, awd2);
      }
    }
    for (int c = 0; c < 32; ++c){
      float wf = sW0[o*E+c], wd = sW1[o*E+c];
      f32x2 wf2 = (f32x2){wf, wf}, wd2 = (f32x2){wd, wd};
      #pragma unroll
      for (int v = 0; v < 3; ++v){
        const float4 ev = *reinterpret_cast<const float4*>(&sNG[(c*3+v)*20 + 4*w0]);
        f32x2 e01 = (f32x2){ev.x, ev.y}, e23 = (f32x2){ev.z, ev.w};
        pA[0][v] = efma(wf2, e01, pA[0][v]);  pA[1][v] = efma(wf2, e23, pA[1][v]);
        qA[0][v] = efma(wd2, e01, qA[0][v]);  qA[1][v] = efma(wd2, e23, qA[1][v]);
      }
    }
    #pragma unroll
    for (int v = 0; v < 3; ++v){
      p[0][v] = pA[0][v].x; p[1][v] = pA[0][v].y; p[2][v] = pA[1][v].x; p[3][v] = pA[1][v].y;
      q[0][v] = qA[0][v].x; q[1][v] = qA[0][v].y; q[2][v] = qA[1][v].x; q[3][v] = qA[1][v].y;
    }
  } else {
    float wr = sW0[o*E+64];
    #pragma unroll
    for (int v = 0; v < 3; ++v){
      const float4 rv = *reinterpret_cast<const float4*>(&sNG[(96+v)*20 + 4*w0]);
      const float* rp = reinterpret_cast<const float*>(&rv);
      #pragma unroll
      for (int r = 0; r < 4; ++r) p[r][v] = fmaf(wr, rp[r], awf[v]);
    }
    for (int c = 0; c < 32; ++c){
      float wf = sW0[o*E+c];
      #pragma unroll
      for (int v = 0; v < 3; ++v){
        const float4 ev = *reinterpret_cast<const float4*>(&sNG[(c*3+v)*20 + 4*w0]);
        const float* ep = reinterpret_cast<const float*>(&ev);
        #pragma unroll
        for (int r = 0; r < 4; ++r) p[r][v] = fmaf(wf, ep[r], p[r][v]);
      }
    }
  }

  if (!PASSB){
    float s = 0.f, s2 = 0.f;
    #pragma unroll
    for (int r = 0; r < 4; ++r){
      float nrm = fadd(sqrtf(fadd(fadd(fmul(p[r][0],p[r][0]),fmul(p[r][1],p[r][1])),fmul(p[r][2],p[r][2]))), 1e-6f);
      s  = fadd(s, nrm);
      s2 = fadd(s2, fmul(nrm,nrm));
    }
    red[tid] = s; red[256+tid] = s2;
    __syncthreads();
    if (tid < 64){
      float a  = ((red[tid]    +red[tid+64])    +red[tid+128])    +red[tid+192];
      float a2 = ((red[256+tid]+red[256+tid+64])+red[256+tid+128])+red[256+tid+192];
      bn_part[(size_t)tid*(B*M) + blk]        = a;   // [o][blk] layout: coalesced in k_bnstats
      bn_part[(size_t)(64+tid)*(B*M) + blk]   = a2;
    }
  } else {
    float mu = bn_stats[o], sc = bn_stats[64+o], bb = bn_bias[o];
    float hs[3] = {0.f,0.f,0.f};
    #pragma unroll
    for (int r = 0; r < 4; ++r){
      float nrm = fadd(sqrtf(fadd(fadd(fmul(p[r][0],p[r][0]),fmul(p[r][1],p[r][1])),fmul(p[r][2],p[r][2]))), 1e-6f);
      float nb  = fadd(fmul(fsub(nrm, mu), sc), bb);
      float rn  = nb / nrm;
      float pn0 = fmul(p[r][0], rn), pn1 = fmul(p[r][1], rn), pn2 = fmul(p[r][2], rn);
      float dot = fadd(fadd(fmul(pn0,q[r][0]),fmul(pn1,q[r][1])),fmul(pn2,q[r][2]));
      float dsq = fadd(fadd(fmul(q[r][0],q[r][0]),fmul(q[r][1],q[r][1])),fmul(q[r][2],q[r][2]));
      float t   = dot / fadd(dsq, 1e-6f);
      bool pos  = (dot >= 0.f);
      float pns[3] = {pn0, pn1, pn2};
      #pragma unroll
      for (int v = 0; v < 3; ++v){
        float inner = pos ? pns[v] : fsub(pns[v], fmul(t, q[r][v]));
        float h = fadd(fmul(0.1f, pns[v]), fmul(0.9f, inner));
        hs[v] = fadd(hs[v], h);
      }
    }
    red[tid] = hs[0]; red[256+tid] = hs[1]; red[512+tid] = hs[2];
    __syncthreads();
    if (tid < 64){
      #pragma unroll
      for (int v = 0; v < 3; ++v){
        const float* rv = red + v*256;
        float tot = ((rv[tid]+rv[tid+64])+rv[tid+128])+rv[tid+192];
        // nf layout (b, v, o, m): coalesced reads in k_zca / k_out
        nf[(((size_t)(b*3+v))*O + tid)*M + m] = fmul(tot, 0.0625f);  // mean over k=16
      }
    }
  }
}

// ---------------- K4: BN statistics reduction ([o][blk] layout: coalesced) ----------------
__global__ __launch_bounds__(256) void k_bnstats(const float* __restrict__ bn_part,
                                                 const float* __restrict__ bnw,
                                                 float* __restrict__ bn_stats){
  __shared__ float r1[256], r2[256];
  int o = blockIdx.x, tid = threadIdx.x;
  float s = 0.f, s2 = 0.f;
  for (int i = tid; i < B*M; i += 256){
    s  += bn_part[(size_t)o*(B*M) + i];
    s2 += bn_part[(size_t)(64+o)*(B*M) + i];
  }
  r1[tid] = s; r2[tid] = s2;
  __syncthreads();
  for (int off = 128; off > 0; off >>= 1){
    if (tid < off){ r1[tid] += r1[tid+off]; r2[tid] += r2[tid+off]; }
    __syncthreads();
  }
  if (tid == 0){
    float cnt = (float)(B*M*KNN);
    float mu  = r1[0] / cnt;
    float var = r2[0]/cnt - mu*mu;
    if (var < 0.f) var = 0.f;
    bn_stats[o]    = mu;
    bn_stats[64+o] = bnw[o] / sqrtf(var + 1e-5f);
  }
}

// ---------------- K6: per-batch ZCA (f64 moments + Jacobi eigensolver) ----------------
__global__ __launch_bounds__(1024) void k_zca(const float* __restrict__ nf,
                                              float* __restrict__ zca){
  int b = blockIdx.x, tid = threadIdx.x;
  const f32x2* xp = (const f32x2*)(nf + ((size_t)(b*3+0))*O*M);
  const f32x2* yp = (const f32x2*)(nf + ((size_t)(b*3+1))*O*M);
  const f32x2* zp = (const f32x2*)(nf + ((size_t)(b*3+2))*O*M);
  double s1[3] = {0,0,0}, s2[6] = {0,0,0,0,0,0};
  for (int i = tid; i < O*M/2; i += 1024){
    f32x2 xv = xp[i], yv = yp[i], zv = zp[i];
    #pragma unroll
    for (int h = 0; h < 2; ++h){
      double x = (double)xv[h], y = (double)yv[h], z = (double)zv[h];
      s1[0]+=x;   s1[1]+=y;   s1[2]+=z;
      s2[0]+=x*x; s2[1]+=x*y; s2[2]+=x*z; s2[3]+=y*y; s2[4]+=y*z; s2[5]+=z*z;
    }
  }
  #pragma unroll
  for (int s = 1; s < 64; s <<= 1){
    #pragma unroll
    for (int j = 0; j < 3; ++j) s1[j] += __shfl_xor(s1[j], s, 64);
    #pragma unroll
    for (int j = 0; j < 6; ++j) s2[j] += __shfl_xor(s2[j], s, 64);
  }
  __shared__ double red[16][9];
  int wid = tid >> 6, lane = tid & 63;
  if (lane == 0){
    red[wid][0]=s1[0]; red[wid][1]=s1[1]; red[wid][2]=s1[2];
    for (int j = 0; j < 6; ++j) red[wid][3+j] = s2[j];
  }
  __syncthreads();
  if (tid == 0){
    double S1[3]={0,0,0}, S2[6]={0,0,0,0,0,0};
    for (int w_ = 0; w_ < 16; ++w_){
      S1[0]+=red[w_][0]; S1[1]+=red[w_][1]; S1[2]+=red[w_][2];
      for (int j = 0; j < 6; ++j) S2[j]+=red[w_][3+j];
    }
    double Mt = (double)(O*M);
    double denom = Mt + 1e-6;
    double A[3][3];
    A[0][0]=(S2[0]-S1[0]*S1[0]/Mt)/denom + 1e-5;
    A[0][1]=A[1][0]=(S2[1]-S1[0]*S1[1]/Mt)/denom;
    A[0][2]=A[2][0]=(S2[2]-S1[0]*S1[2]/Mt)/denom;
    A[1][1]=(S2[3]-S1[1]*S1[1]/Mt)/denom + 1e-5;
    A[1][2]=A[2][1]=(S2[4]-S1[1]*S1[2]/Mt)/denom;
    A[2][2]=(S2[5]-S1[2]*S1[2]/Mt)/denom + 1e-5;
    double V[3][3]={{1,0,0},{0,1,0},{0,0,1}};
    for (int sweep = 0; sweep < 30; ++sweep){
      double offd = fabs(A[0][1])+fabs(A[0][2])+fabs(A[1][2]);
      if (offd < 1e-15) break;
      for (int pi = 0; pi < 3; ++pi) for (int qi = pi+1; qi < 3; ++qi){
        double apq = A[pi][qi];
        if (fabs(apq) < 1e-18) continue;
        double app = A[pi][pi], aqq = A[qi][qi];
        double theta = (aqq - app)/(2.0*apq);
        double t = ((theta >= 0) ? 1.0 : -1.0)/(fabs(theta) + sqrt(theta*theta + 1.0));
        double cth = 1.0/sqrt(t*t + 1.0), sth = t*cth;
        for (int r_ = 0; r_ < 3; ++r_){
          double arp=A[r_][pi], arq=A[r_][qi];
          A[r_][pi]=cth*arp - sth*arq;
          A[r_][qi]=sth*arp + cth*arq;
        }
        for (int c_ = 0; c_ < 3; ++c_){
          double apc=A[pi][c_], aqc=A[qi][c_];
          A[pi][c_]=cth*apc - sth*aqc;
          A[qi][c_]=sth*apc + cth*aqc;
        }
        for (int r_ = 0; r_ < 3; ++r_){
          double vrp=V[r_][pi], vrq=V[r_][qi];
          V[r_][pi]=cth*vrp - sth*vrq;
          V[r_][qi]=sth*vrp + cth*vrq;
        }
      }
    }
    double wv[3] = {A[0][0], A[1][1], A[2][2]};
    for (int j = 0; j < 3; ++j) if (wv[j] < 1e-5) wv[j] = 1e-5;
    double is[3] = {1.0/sqrt(wv[0]), 1.0/sqrt(wv[1]), 1.0/sqrt(wv[2])};
    for (int i = 0; i < 3; ++i)
      for (int j = 0; j < 3; ++j){
        double wz = V[i][0]*is[0]*V[j][0] + V[i][1]*is[1]*V[j][1] + V[i][2]*is[2]*V[j][2];
        zca[b*12 + i*3 + j] = (float)wz;
      }
    for (int j = 0; j < 3; ++j) zca[b*12 + 9 + j] = (float)(S1[j]/Mt);
  }
}

// ---------------- K7: whiten + gamma (nf (b,v,o,m) -> out (b,o,v,m)) ----------------
__global__ __launch_bounds__(256) void k_out(const float* __restrict__ nf,
                                             const float* __restrict__ zca,
                                             const float* __restrict__ gamma,
                                             float* __restrict__ out){
  int i = blockIdx.x*256 + threadIdx.x;   // B*O*M
  if (i >= B*O*M) return;
  int m = i & 2047;
  int bo = i >> 11;
  int o = bo & 63;
  int b = bo >> 6;
  const float* W  = zca + b*12;
  const float* mn = W + 9;
  size_t planeO = (size_t)O*M;
  float c0 = fsub(nf[((size_t)(b*3+0))*planeO + (size_t)o*M + m], mn[0]);
  float c1 = fsub(nf[((size_t)(b*3+1))*planeO + (size_t)o*M + m], mn[1]);
  float c2 = fsub(nf[((size_t)(b*3+2))*planeO + (size_t)o*M + m], mn[2]);
  float g = gamma[o];
  #pragma unroll
  for (int v = 0; v < 3; ++v){
    float val = fadd(fadd(fmul(W[v*3+0], c0), fmul(W[v*3+1], c1)), fmul(W[v*3+2], c2));
    out[(size_t)bo*3*M + (size_t)v*M + m] = fmul(val, g);
  }
}

extern "C" void kernel_launch(void* const* d_in, const int* in_sizes, int n_in,
                              void* d_out, int out_size, void* d_ws, size_t ws_size,
                              hipStream_t stream){
  const float* xyz  = (const float*)d_in[0];
  const float* feat = (const float*)d_in[1];
  const float* Wf   = (const float*)d_in[2];
  const float* Wd   = (const float*)d_in[3];
  const float* bnw  = (const float*)d_in[4];
  const float* bnb  = (const float*)d_in[5];
  const float* gam  = (const float*)d_in[6];
  float* out      = (float*)d_out;
  float* newxyz   = out;              // (B,M,3)
  float* conv_out = out + (size_t)B*M*3;

  char* ws = (char*)d_ws;
  size_t off = 0;
  auto alloc = [&](size_t bytes)->void*{
    void* p = ws + off;
    off = (off + bytes + 255) & ~(size_t)255;
    return p;
  };
  float* featT    = (float*)alloc((size_t)B*N*96*4);
  float* xsoa     = (float*)alloc((size_t)B*3*N*4);
  float* sx       = (float*)alloc((size_t)B*N*4);
  int*   fpsi     = (int*)  alloc((size_t)B*M*4);
  int*   gidx     = (int*)  alloc((size_t)B*M*KNN*4);
  float* bn_part  = (float*)alloc((size_t)B*M*128*4);
  float* bn_stats = (float*)alloc(128*4);
  float* nf       = (float*)alloc((size_t)B*O*3*M*4);
  float* zca      = (float*)alloc(B*12*4);
  float* slx      = (float*)alloc((size_t)B*N*4);
  float* sly      = (float*)alloc((size_t)B*N*4);
  float* slz      = (float*)alloc((size_t)B*N*4);
  unsigned short* sidx = (unsigned short*)alloc((size_t)B*N*2);
  float4* gstat   = (float4*)alloc((size_t)B*NG*16);

  hipLaunchKernelGGL(k_transpose, dim3(B*(N/64)), dim3(256), 0, stream, feat, featT);
  hipLaunchKernelGGL(k_xyz_pre,   dim3(B*N/256),  dim3(256), 0, stream, xyz, xsoa, sx);
  hipLaunchKernelGGL(k_sort,      dim3(B),        dim3(256), 0, stream, xsoa, slx, sly, slz, sidx);
  hipLaunchKernelGGL(k_gstat,     dim3(B*NG),     dim3(64),  0, stream, slx, sly, slz, gstat);
  hipLaunchKernelGGL(k_fps,       dim3(B),        dim3(256), 0, stream,
                     xsoa, slx, sly, slz, sidx, gstat, fpsi, newxyz);
  hipLaunchKernelGGL(k_knn,       dim3(B*M/4),    dim3(256), 0, stream, xsoa, sx, newxyz, gidx);
  hipLaunchKernelGGL((k_conv<0>), dim3(B*M),      dim3(256), 0, stream,
                     featT, xsoa, newxyz, fpsi, gidx, Wf, Wd, bn_stats, bnb, bn_part, nf);
  hipLaunchKernelGGL(k_bnstats,   dim3(O),        dim3(256), 0, stream, bn_part, bnw, bn_stats);
  hipLaunchKernelGGL((k_conv<1>), dim3(B*M),      dim3(256), 0, stream,
                     featT, xsoa, newxyz, fpsi, gidx, Wf, Wd, bn_stats, bnb, bn_part, nf);
  hipLaunchKernelGGL(k_zca,       dim3(B),        dim3(1024),0, stream, nf, zca);
  hipLaunchKernelGGL(k_out,       dim3((B*O*M)/256), dim3(256), 0, stream, nf, zca, gam, conv_out);
}

// Round 11
// 5952.750 us; speedup vs baseline: 1.1079x; 1.1079x over previous
//
#include <hip/hip_runtime.h>
#include <stdint.h>

#define DI __device__ __forceinline__

static constexpr int B   = 4;
static constexpr int N   = 8192;
static constexpr int M   = 2048;
static constexpr int KNN = 16;
static constexpr int O   = 64;
static constexpr int E   = 65;   // 2C+1 edge channels
static constexpr int NG  = 128;  // FPS groups per batch (64 pts each)

typedef float f32x2 __attribute__((ext_vector_type(2)));

DI float fadd(float a, float b){ return __fadd_rn(a,b); }
DI float fsub(float a, float b){ return __fsub_rn(a,b); }
DI float fmul(float a, float b){ return __fmul_rn(a,b); }

#if __has_builtin(__builtin_elementwise_fma)
DI f32x2 efma(f32x2 a, f32x2 b, f32x2 c){ return __builtin_elementwise_fma(a,b,c); }
#else
DI f32x2 efma(f32x2 a, f32x2 b, f32x2 c){ return (f32x2){fmaf(a.x,b.x,c.x), fmaf(a.y,b.y,c.y)}; }
#endif

// one DPP max step: t = max(t, dpp_perm(t))  (invalid source -> 0, fine for >=0 data)
template<int CTRL>
DI float dppmax(float v){
  int t = __builtin_amdgcn_update_dpp(0, __float_as_int(v), CTRL, 0xf, 0xf, true);
  return fmaxf(v, __int_as_float(t));
}
DI float wave_max_bcast63(float v){
  v = dppmax<0xB1>(v);   // quad_perm xor1
  v = dppmax<0x4E>(v);   // quad_perm xor2
  v = dppmax<0x141>(v);  // row_half_mirror
  v = dppmax<0x140>(v);  // row_mirror
  v = dppmax<0x142>(v);  // row_bcast15
  v = dppmax<0x143>(v);  // row_bcast31 -> full max in lane 63
  return __int_as_float(__builtin_amdgcn_readlane(__float_as_int(v), 63));
}
// int min-reduce: invalid source keeps OWN value (old=v, bound_ctrl=false) so min unaffected
template<int CTRL>
DI int dppmin_i(int v){
  int t = __builtin_amdgcn_update_dpp(v, v, CTRL, 0xf, 0xf, false);
  return t < v ? t : v;
}
DI int wave_min_bcast63_i(int v){
  v = dppmin_i<0xB1>(v);
  v = dppmin_i<0x4E>(v);
  v = dppmin_i<0x141>(v);
  v = dppmin_i<0x140>(v);
  v = dppmin_i<0x142>(v);
  v = dppmin_i<0x143>(v);
  return __builtin_amdgcn_readlane(v, 63);
}

DI unsigned mort1(unsigned x){   // spread 4 bits to every 3rd position
  return (x & 1u) | ((x & 2u) << 2) | ((x & 4u) << 4) | ((x & 8u) << 6);
}

// ---------------- K0a: feat (B,96,N) -> featT (B,N,96) ----------------
__global__ __launch_bounds__(256) void k_transpose(const float* __restrict__ feat,
                                                   float* __restrict__ featT){
  __shared__ float tile[64*97];
  int blk = blockIdx.x;
  int b = blk / (N/64);
  int n0 = (blk % (N/64)) * 64;
  const float* fb = feat + (size_t)b*96*N;
  for (int e = threadIdx.x; e < 96*64; e += 256){
    int cv = e >> 6, nn = e & 63;
    tile[nn*97 + cv] = fb[(size_t)cv*N + n0 + nn];
  }
  __syncthreads();
  float* ob = featT + ((size_t)b*N + n0)*96;
  for (int e = threadIdx.x; e < 96*64; e += 256){
    int nn = e / 96, cv = e - nn*96;
    ob[e] = tile[nn*97 + cv];
  }
}

// ---------------- K0b: xyz -> SoA + per-point squared norms ----------------
__global__ __launch_bounds__(256) void k_xyz_pre(const float* __restrict__ xyz,
                                                 float* __restrict__ xsoa,
                                                 float* __restrict__ sx){
  int i = blockIdx.x*256 + threadIdx.x;
  if (i >= B*N) return;
  int b = i >> 13, n = i & 8191;
  float x = xyz[(size_t)i*3+0], y = xyz[(size_t)i*3+1], z = xyz[(size_t)i*3+2];
  xsoa[((size_t)b*3+0)*N + n] = x;
  xsoa[((size_t)b*3+1)*N + n] = y;
  xsoa[((size_t)b*3+2)*N + n] = z;
  sx[i] = fadd(fadd(fmul(x,x),fmul(y,y)),fmul(z,z));   // numpy order ((x2+y2)+z2)
}

// ---------------- K1a: Morton counting-sort (per batch) ----------------
__global__ __launch_bounds__(256) void k_sort(const float* __restrict__ xsoa,
                                              float* __restrict__ slx, float* __restrict__ sly,
                                              float* __restrict__ slz,
                                              unsigned short* __restrict__ sidx){
  int b = blockIdx.x, tid = threadIdx.x;
  const float* X = xsoa + (size_t)b*3*N;
  __shared__ unsigned hist[4096];
  __shared__ unsigned basep[4096];
  __shared__ unsigned tot[256];
  for (int i = tid; i < 4096; i += 256) hist[i] = 0;
  __syncthreads();
  unsigned short cell[32];
  #pragma unroll 4
  for (int j = 0; j < 32; ++j){
    int n = tid*32 + j;
    float x = X[n], y = X[N+n], z = X[2*N+n];
    int ix = (int)floorf((x + 6.f) * (4.f/3.f)); ix = ix < 0 ? 0 : (ix > 15 ? 15 : ix);
    int iy = (int)floorf((y + 6.f) * (4.f/3.f)); iy = iy < 0 ? 0 : (iy > 15 ? 15 : iy);
    int iz = (int)floorf((z + 6.f) * (4.f/3.f)); iz = iz < 0 ? 0 : (iz > 15 ? 15 : iz);
    unsigned c = mort1((unsigned)ix) | (mort1((unsigned)iy) << 1) | (mort1((unsigned)iz) << 2);
    cell[j] = (unsigned short)c;
    atomicAdd(&hist[c], 1u);
  }
  __syncthreads();
  unsigned run = 0;
  for (int i = 0; i < 16; ++i){ unsigned h = hist[tid*16+i]; basep[tid*16+i] = run; run += h; }
  tot[tid] = run;
  __syncthreads();
  for (int off = 1; off < 256; off <<= 1){
    unsigned add = (tid >= off) ? tot[tid-off] : 0u;
    __syncthreads();
    tot[tid] += add;
    __syncthreads();
  }
  unsigned cb = (tid == 0) ? 0u : tot[tid-1];
  for (int i = 0; i < 16; ++i) basep[tid*16+i] += cb;
  __syncthreads();
  for (int i = tid; i < 4096; i += 256) hist[i] = 0;
  __syncthreads();
  #pragma unroll 4
  for (int j = 0; j < 32; ++j){
    int n = tid*32 + j;
    unsigned c = cell[j];
    unsigned pos = basep[c] + atomicAdd(&hist[c], 1u);
    slx[(size_t)b*N + pos] = X[n];
    sly[(size_t)b*N + pos] = X[N+n];
    slz[(size_t)b*N + pos] = X[2*N+n];
    sidx[(size_t)b*N + pos] = (unsigned short)n;
  }
}

// ---------------- K1b: per-group centroid + conservative radius ----------------
__global__ __launch_bounds__(64) void k_gstat(const float* __restrict__ slx,
                                              const float* __restrict__ sly,
                                              const float* __restrict__ slz,
                                              float4* __restrict__ gstat){
  int g = blockIdx.x;              // 0 .. B*NG-1
  int tid = threadIdx.x;
  size_t j = (size_t)g*64 + tid;
  float x = slx[j], y = sly[j], z = slz[j];
  float sxv = x, syv = y, szv = z;
  #pragma unroll
  for (int s = 1; s < 64; s <<= 1){
    sxv += __shfl_xor(sxv, s, 64); syv += __shfl_xor(syv, s, 64); szv += __shfl_xor(szv, s, 64);
  }
  float cx = sxv*(1.f/64.f), cy = syv*(1.f/64.f), cz = szv*(1.f/64.f);
  float dx = x-cx, dy = y-cy, dz = z-cz;
  float d = sqrtf(dx*dx + dy*dy + dz*dz);
  #pragma unroll
  for (int s = 1; s < 64; s <<= 1) d = fmaxf(d, __shfl_xor(d, s, 64));
  if (tid == 0) gstat[g] = make_float4(cx, cy, cz, fmaf(d, 1.0001f, 1e-7f));  // radius rounded UP
}

// ---------------- K1c: pruned FPS, register-resident (exact, tie-exact) ----------------
// R10's pruning predicate + tie-break (both PASSED) on R3's register-resident
// structure (fast). Thread (wave w, lane l) owns slot s <-> sorted point
// w*2048 + s*64 + l: coords + dist in 128 VGPRs, STATIC indices only.
// Update = #pragma unroll over 32 slots gated by WAVE-UNIFORM scalar branch
// (mask>>s)&1 — skipped slot ~3 cyc, no LDS in update path, per-slot DPP
// chains independent => ILP. gmaxl refreshed whenever group active => always
// exact (inactive groups' dist unchanged). Tail = R3's proven shape: publish
// (val, origidx, sortedpos); post-barrier 4-way select + 3 uniform LDS gathers.
__global__ __launch_bounds__(256, 1) void k_fps(const float* __restrict__ xsoa,
                                                const float* __restrict__ slx,
                                                const float* __restrict__ sly,
                                                const float* __restrict__ slz,
                                                const unsigned short* __restrict__ sidx,
                                                const float4* __restrict__ gstat,
                                                int* __restrict__ fps_idx,
                                                float* __restrict__ newxyz){
  #pragma clang fp contract(off)
  int b = blockIdx.x, tid = threadIdx.x;
  int lane = tid & 63, wid = tid >> 6;
  __shared__ float lxl[N], lyl[N], lzl[N];      // sorted coords, read-only after init (96 KB)
  __shared__ unsigned short sidxl[N];           // 16 KB
  __shared__ __align__(16) float4 gst[NG];
  __shared__ float gmaxl[NG];
  __shared__ uint4 pub[2][4];

  const float* SXp = slx + (size_t)b*N;
  const float* SYp = sly + (size_t)b*N;
  const float* SZp = slz + (size_t)b*N;
  const unsigned short* SIp = sidx + (size_t)b*N;
  for (int j = tid; j < N; j += 256){
    lxl[j] = SXp[j]; lyl[j] = SYp[j]; lzl[j] = SZp[j];
    sidxl[j] = SIp[j];
  }
  if (tid < NG){ gst[tid] = gstat[b*NG + tid]; gmaxl[tid] = 1e10f; }

  float px[32], py[32], pz[32], ds[32];
  #pragma unroll
  for (int s = 0; s < 32; ++s){
    int j = (wid << 11) + (s << 6) + lane;     // sorted position
    px[s] = SXp[j]; py[s] = SYp[j]; pz[s] = SZp[j];
    ds[s] = 1e10f;
  }
  const float* X = xsoa + (size_t)b*3*N;
  float cx = X[0], cy = X[N], cz = X[2*N];     // original index 0 = first centroid
  if (tid == 0){
    fps_idx[b*M] = 0;
    newxyz[(size_t)(b*M)*3+0] = cx;
    newxyz[(size_t)(b*M)*3+1] = cy;
    newxyz[(size_t)(b*M)*3+2] = cz;
  }
  __syncthreads();

  for (int it = 1; it < M; ++it){
    // ---- bound phase (lane-parallel over this wave's 32 groups; both 32-halves agree)
    int g = (wid << 5) + (lane & 31);
    float4 gs = gst[g];
    float gmv = gmaxl[g];
    float bdx = fsub(gs.x, cx), bdy = fsub(gs.y, cy), bdz = fsub(gs.z, cz);
    float D   = sqrtf(fadd(fadd(fmul(bdx,bdx), fmul(bdy,bdy)), fmul(bdz,bdz)));
    float lb  = fmaxf(fsub(fmul(D, 0.99999f), gs.w), 0.f);
    float lb2 = fmul(fmul(lb, lb), 0.9999f);
    bool act  = !(lb2 > gmv);
    unsigned mask = (unsigned)(__ballot(act) & 0xFFFFFFFFull);

    // ---- update phase: fully unrolled, wave-uniform branch per slot, registers only
    #pragma unroll
    for (int s = 0; s < 32; ++s){
      if (mask & (1u << s)){
        float ddx = fsub(px[s], cx), ddy = fsub(py[s], cy), ddz = fsub(pz[s], cz);
        float d   = fadd(fadd(fmul(ddx,ddx), fmul(ddy,ddy)), fmul(ddz,ddz));  // numpy op order
        float nd  = fminf(ds[s], d);
        ds[s] = nd;
        float gm_ = wave_max_bcast63(nd);          // exact refreshed group max
        if (lane == 0) gmaxl[(wid << 5) + s] = gm_;
      }
    }

    // ---- wave winner value (max over own 32 group maxima; exact for inactive too)
    float gv = gmaxl[(wid << 5) + (lane & 31)];
    float wm = wave_max_bcast63(gv);

    // ---- tie-exact resolve: per-lane min ORIGINAL index among ds[s]==wm (static scan)
    int bestoi = 0x7FFFFFFF, bestbs = 0;
    #pragma unroll
    for (int s = 0; s < 32; ++s){
      if (ds[s] == wm){                            // divergent, rare
        int bs_ = (wid << 11) + (s << 6) + lane;
        int oi  = (int)sidxl[bs_];
        if (oi < bestoi){ bestoi = oi; bestbs = bs_; }
      }
    }
    int wi = wave_min_bcast63_i(bestoi);           // wave-min original index (exists: wm is own max)
    int buf = it & 1;
    if (bestoi == wi && wi != 0x7FFFFFFF){         // exactly one lane (orig indices unique)
      pub[buf][wid] = make_uint4(__float_as_uint(wm), (unsigned)wi, (unsigned)bestbs, 0u);
    }
    __syncthreads();

    // ---- global select: (value desc, original index asc) — exact numpy argmax
    uint4 p0 = pub[buf][0], p1 = pub[buf][1], p2 = pub[buf][2], p3 = pub[buf][3];
    float v0 = __uint_as_float(p0.x), v1 = __uint_as_float(p1.x);
    float v2 = __uint_as_float(p2.x), v3 = __uint_as_float(p3.x);
    if (v1 > v0 || (v1 == v0 && p1.y < p0.y)){ p0 = p1; v0 = v1; }
    if (v2 > v0 || (v2 == v0 && p2.y < p0.y)){ p0 = p2; v0 = v2; }
    if (v3 > v0 || (v3 == v0 && p3.y < p0.y)){ p0 = p3; v0 = v3; }
    int bsw = (int)p0.z;
    cx = lxl[bsw]; cy = lyl[bsw]; cz = lzl[bsw];   // 3 uniform broadcast LDS reads (R3 tail)
    if (tid == 0){
      fps_idx[b*M + it] = (int)p0.y;
      newxyz[(size_t)(b*M+it)*3+0] = cx;
      newxyz[(size_t)(b*M+it)*3+1] = cy;
      newxyz[(size_t)(b*M+it)*3+2] = cz;
    }
  }
}

// ---------------- K2: brute-force kNN (k=16), one wave per query ----------------
__global__ __launch_bounds__(256) void k_knn(const float* __restrict__ xsoa,
                                             const float* __restrict__ sx,
                                             const float* __restrict__ newxyz,
                                             int* __restrict__ gidx){
  __shared__ unsigned long long heap[4][64][17];
  __shared__ unsigned long long outk[4][16];
  int tid = threadIdx.x;
  int lane = tid & 63, wv = tid >> 6;
  int w = blockIdx.x*4 + wv;                 // query id, B*M total
  int b = w >> 11;
  const float* X  = xsoa + (size_t)b*3*N;
  const float* SX = sx   + (size_t)b*N;
  float qx = newxyz[(size_t)w*3+0], qy = newxyz[(size_t)w*3+1], qz = newxyz[(size_t)w*3+2];
  float sn = fadd(fadd(fmul(qx,qx),fmul(qy,qy)),fmul(qz,qz));

  unsigned long long cand[16];
  #pragma unroll
  for (int i = 0; i < 16; ++i) cand[i] = 0xFFFFFFFFFFFFFFFFull;

  for (int r = 0; r < 128; ++r){
    int n = (r << 6) + lane;
    float p0 = fmul(qx, X[n]), p1 = fmul(qy, X[N+n]), p2 = fmul(qz, X[2*N+n]);
    float dot = fadd(fadd(p0, p1), p2);
    float d2  = fsub(fadd(sn, SX[n]), fmul(2.0f, dot));   // reference expansion, matching op order
    unsigned u = __float_as_uint(d2);
    u ^= ((unsigned)((int)u >> 31)) | 0x80000000u;        // monotone f32->u32
    unsigned long long key = ((unsigned long long)u << 32) | (unsigned)n;
    if (key < cand[15]){
      #pragma unroll
      for (int i = 0; i < 16; ++i){                        // branch-free sorted insertion
        unsigned long long a = cand[i];
        bool sw = key < a;
        unsigned long long lo = sw ? key : a;
        unsigned long long hi = sw ? a : key;
        cand[i] = lo; key = hi;
      }
    }
  }
  #pragma unroll
  for (int i = 0; i < 16; ++i) heap[wv][lane][i] = cand[i];
  unsigned long long my = cand[0];
  int head = 0;
  for (int round = 0; round < 16; ++round){                // 16x extract-min across wave
    unsigned long long k = my;
    #pragma unroll
    for (int s = 1; s < 64; s <<= 1){
      unsigned long long o_ = __shfl_xor(k, s, 64);
      if (o_ < k) k = o_;
    }
    if (my == k){
      ++head;
      my = (head < 16) ? heap[wv][lane][head] : 0xFFFFFFFFFFFFFFFFull;
    }
    if (lane == 0) outk[wv][round] = k;
  }
  __syncthreads();
  if (lane < 16) gidx[(size_t)w*16 + lane] = (int)(unsigned)(outk[wv][lane] & 0xFFFFFFFFull);
}

// ---------------- K3/K5: edge conv, anchor-folded form ----------------
template<int PASSB>
__global__ __launch_bounds__(256) void k_conv(const float* __restrict__ featT,
                                              const float* __restrict__ xsoa,
                                              const float* __restrict__ newxyz,
                                              const int*   __restrict__ fps_idx,
                                              const int*   __restrict__ gidx,
                                              const float* __restrict__ Wf,
                                              const float* __restrict__ Wd,
                                              const float* __restrict__ bn_stats,  // mu[64], scale[64]
                                              const float* __restrict__ bn_bias,
                                              float* __restrict__ bn_part,
                                              float* __restrict__ nf){
  __shared__ float sW0[O*E];
  __shared__ float sW1[PASSB ? O*E : 1];
  __shared__ __align__(16) float sNG[99*20];   // rows 0..95: neigh cv; rows 96..98: rel v
  __shared__ float sA[96];
  __shared__ float red[3*256];

  int blk = blockIdx.x;                // b*M + m
  int b = blk >> 11, m = blk & 2047;
  int tid = threadIdx.x;

  for (int e = tid; e < O*E; e += 256) sW0[e] = Wf[e];
  if (PASSB){ for (int e = tid; e < O*E; e += 256) sW1[e] = Wd[e]; }
  int aidx = fps_idx[blk];
  if (tid < 96) sA[tid] = featT[((size_t)(b*N) + aidx)*96 + tid];

  #pragma unroll 4
  for (int kk = 0; kk < KNN; ++kk){
    int n = gidx[(size_t)blk*KNN + kk];
    if (tid < 96){
      sNG[tid*20 + kk] = featT[((size_t)(b*N) + n)*96 + tid];
    } else if (tid < 99){
      int v = tid - 96;
      sNG[(96+v)*20 + kk] = fsub(xsoa[((size_t)(b*3+v))*N + n], newxyz[(size_t)blk*3 + v]);
    }
  }
  __syncthreads();

  int o  = tid & 63;
  int w0 = tid >> 6;           // wave owns kk = 4*w0 + r, r=0..3

  float awf[3] = {0,0,0}, awd[3] = {0,0,0};
  for (int c = 0; c < 32; ++c){
    float df = sW0[o*E+32+c] - sW0[o*E+c];
    float dd = PASSB ? (sW1[o*E+32+c] - sW1[o*E+c]) : 0.f;
    #pragma unroll
    for (int v = 0; v < 3; ++v){
      float a = sA[c*3+v];
      awf[v] = fmaf(df, a, awf[v]);
      if (PASSB) awd[v] = fmaf(dd, a, awd[v]);
    }
  }

  float p[4][3], q[4][3];
  if (PASSB){
    f32x2 pA[2][3], qA[2][3];
    {
      float wr  = sW0[o*E+64];
      float wrd = sW1[o*E+64];
      f32x2 wr2  = (f32x2){wr, wr};
      f32x2 wrd2 = (f32x2){wrd, wrd};
      #pragma unroll
      for (int v = 0; v < 3; ++v){
        const float4 rv = *reinterpret_cast<const float4*>(&sNG[(96+v)*20 + 4*w0]);
        f32x2 r01 = (f32x2){rv.x, rv.y}, r23 = (f32x2){rv.z, rv.w};
        f32x2 awf2 = (f32x2){awf[v], awf[v]};
        f32x2 awd2 = (f32x2){awd[v], awd[v]};
        pA[0][v] = efma(wr2,  r01, awf2);  pA[1][v] = efma(wr2,  r23, awf2);
        qA[0][v] = efma(wrd2, r01, awd2);  qA[1][v] = efma(wrd2, r23, awd2);
      }
    }
    for (int c = 0; c < 32; ++c){
      float wf = sW0[o*E+c], wd = sW1[o*E+c];
      f32x2 wf2 = (f32x2){wf, wf}, wd2 = (f32x2){wd, wd};
      #pragma unroll
      for (int v = 0; v < 3; ++v){
        const float4 ev = *reinterpret_cast<const float4*>(&sNG[(c*3+v)*20 + 4*w0]);
        f32x2 e01 = (f32x2){ev.x, ev.y}, e23 = (f32x2){ev.z, ev.w};
        pA[0][v] = efma(wf2, e01, pA[0][v]);  pA[1][v] = efma(wf2, e23, pA[1][v]);
        qA[0][v] = efma(wd2, e01, qA[0][v]);  qA[1][v] = efma(wd2, e23, qA[1][v]);
      }
    }
    #pragma unroll
    for (int v = 0; v < 3; ++v){
      p[0][v] = pA[0][v].x; p[1][v] = pA[0][v].y; p[2][v] = pA[1][v].x; p[3][v] = pA[1][v].y;
      q[0][v] = qA[0][v].x; q[1][v] = qA[0][v].y; q[2][v] = qA[1][v].x; q[3][v] = qA[1][v].y;
    }
  } else {
    float wr = sW0[o*E+64];
    #pragma unroll
    for (int v = 0; v < 3; ++v){
      const float4 rv = *reinterpret_cast<const float4*>(&sNG[(96+v)*20 + 4*w0]);
      const float* rp = reinterpret_cast<const float*>(&rv);
      #pragma unroll
      for (int r = 0; r < 4; ++r) p[r][v] = fmaf(wr, rp[r], awf[v]);
    }
    for (int c = 0; c < 32; ++c){
      float wf = sW0[o*E+c];
      #pragma unroll
      for (int v = 0; v < 3; ++v){
        const float4 ev = *reinterpret_cast<const float4*>(&sNG[(c*3+v)*20 + 4*w0]);
        const float* ep = reinterpret_cast<const float*>(&ev);
        #pragma unroll
        for (int r = 0; r < 4; ++r) p[r][v] = fmaf(wf, ep[r], p[r][v]);
      }
    }
  }

  if (!PASSB){
    float s = 0.f, s2 = 0.f;
    #pragma unroll
    for (int r = 0; r < 4; ++r){
      float nrm = fadd(sqrtf(fadd(fadd(fmul(p[r][0],p[r][0]),fmul(p[r][1],p[r][1])),fmul(p[r][2],p[r][2]))), 1e-6f);
      s  = fadd(s, nrm);
      s2 = fadd(s2, fmul(nrm,nrm));
    }
    red[tid] = s; red[256+tid] = s2;
    __syncthreads();
    if (tid < 64){
      float a  = ((red[tid]    +red[tid+64])    +red[tid+128])    +red[tid+192];
      float a2 = ((red[256+tid]+red[256+tid+64])+red[256+tid+128])+red[256+tid+192];
      bn_part[(size_t)tid*(B*M) + blk]        = a;   // [o][blk] layout: coalesced in k_bnstats
      bn_part[(size_t)(64+tid)*(B*M) + blk]   = a2;
    }
  } else {
    float mu = bn_stats[o], sc = bn_stats[64+o], bb = bn_bias[o];
    float hs[3] = {0.f,0.f,0.f};
    #pragma unroll
    for (int r = 0; r < 4; ++r){
      float nrm = fadd(sqrtf(fadd(fadd(fmul(p[r][0],p[r][0]),fmul(p[r][1],p[r][1])),fmul(p[r][2],p[r][2]))), 1e-6f);
      float nb  = fadd(fmul(fsub(nrm, mu), sc), bb);
      float rn  = nb / nrm;
      float pn0 = fmul(p[r][0], rn), pn1 = fmul(p[r][1], rn), pn2 = fmul(p[r][2], rn);
      float dot = fadd(fadd(fmul(pn0,q[r][0]),fmul(pn1,q[r][1])),fmul(pn2,q[r][2]));
      float dsq = fadd(fadd(fmul(q[r][0],q[r][0]),fmul(q[r][1],q[r][1])),fmul(q[r][2],q[r][2]));
      float t   = dot / fadd(dsq, 1e-6f);
      bool pos  = (dot >= 0.f);
      float pns[3] = {pn0, pn1, pn2};
      #pragma unroll
      for (int v = 0; v < 3; ++v){
        float inner = pos ? pns[v] : fsub(pns[v], fmul(t, q[r][v]));
        float h = fadd(fmul(0.1f, pns[v]), fmul(0.9f, inner));
        hs[v] = fadd(hs[v], h);
      }
    }
    red[tid] = hs[0]; red[256+tid] = hs[1]; red[512+tid] = hs[2];
    __syncthreads();
    if (tid < 64){
      #pragma unroll
      for (int v = 0; v < 3; ++v){
        const float* rv = red + v*256;
        float tot = ((rv[tid]+rv[tid+64])+rv[tid+128])+rv[tid+192];
        // nf layout (b, v, o, m): coalesced reads in k_zca / k_out
        nf[(((size_t)(b*3+v))*O + tid)*M + m] = fmul(tot, 0.0625f);  // mean over k=16
      }
    }
  }
}

// ---------------- K4: BN statistics reduction ([o][blk] layout: coalesced) ----------------
__global__ __launch_bounds__(256) void k_bnstats(const float* __restrict__ bn_part,
                                                 const float* __restrict__ bnw,
                                                 float* __restrict__ bn_stats){
  __shared__ float r1[256], r2[256];
  int o = blockIdx.x, tid = threadIdx.x;
  float s = 0.f, s2 = 0.f;
  for (int i = tid; i < B*M; i += 256){
    s  += bn_part[(size_t)o*(B*M) + i];
    s2 += bn_part[(size_t)(64+o)*(B*M) + i];
  }
  r1[tid] = s; r2[tid] = s2;
  __syncthreads();
  for (int off = 128; off > 0; off >>= 1){
    if (tid < off){ r1[tid] += r1[tid+off]; r2[tid] += r2[tid+off]; }
    __syncthreads();
  }
  if (tid == 0){
    float cnt = (float)(B*M*KNN);
    float mu  = r1[0] / cnt;
    float var = r2[0]/cnt - mu*mu;
    if (var < 0.f) var = 0.f;
    bn_stats[o]    = mu;
    bn_stats[64+o] = bnw[o] / sqrtf(var + 1e-5f);
  }
}

// ---------------- K6: per-batch ZCA (f64 moments + Jacobi eigensolver) ----------------
__global__ __launch_bounds__(1024) void k_zca(const float* __restrict__ nf,
                                              float* __restrict__ zca){
  int b = blockIdx.x, tid = threadIdx.x;
  const f32x2* xp = (const f32x2*)(nf + ((size_t)(b*3+0))*O*M);
  const f32x2* yp = (const f32x2*)(nf + ((size_t)(b*3+1))*O*M);
  const f32x2* zp = (const f32x2*)(nf + ((size_t)(b*3+2))*O*M);
  double s1[3] = {0,0,0}, s2[6] = {0,0,0,0,0,0};
  for (int i = tid; i < O*M/2; i += 1024){
    f32x2 xv = xp[i], yv = yp[i], zv = zp[i];
    #pragma unroll
    for (int h = 0; h < 2; ++h){
      double x = (double)xv[h], y = (double)yv[h], z = (double)zv[h];
      s1[0]+=x;   s1[1]+=y;   s1[2]+=z;
      s2[0]+=x*x; s2[1]+=x*y; s2[2]+=x*z; s2[3]+=y*y; s2[4]+=y*z; s2[5]+=z*z;
    }
  }
  #pragma unroll
  for (int s = 1; s < 64; s <<= 1){
    #pragma unroll
    for (int j = 0; j < 3; ++j) s1[j] += __shfl_xor(s1[j], s, 64);
    #pragma unroll
    for (int j = 0; j < 6; ++j) s2[j] += __shfl_xor(s2[j], s, 64);
  }
  __shared__ double red[16][9];
  int wid = tid >> 6, lane = tid & 63;
  if (lane == 0){
    red[wid][0]=s1[0]; red[wid][1]=s1[1]; red[wid][2]=s1[2];
    for (int j = 0; j < 6; ++j) red[wid][3+j] = s2[j];
  }
  __syncthreads();
  if (tid == 0){
    double S1[3]={0,0,0}, S2[6]={0,0,0,0,0,0};
    for (int w_ = 0; w_ < 16; ++w_){
      S1[0]+=red[w_][0]; S1[1]+=red[w_][1]; S1[2]+=red[w_][2];
      for (int j = 0; j < 6; ++j) S2[j]+=red[w_][3+j];
    }
    double Mt = (double)(O*M);
    double denom = Mt + 1e-6;
    double A[3][3];
    A[0][0]=(S2[0]-S1[0]*S1[0]/Mt)/denom + 1e-5;
    A[0][1]=A[1][0]=(S2[1]-S1[0]*S1[1]/Mt)/denom;
    A[0][2]=A[2][0]=(S2[2]-S1[0]*S1[2]/Mt)/denom;
    A[1][1]=(S2[3]-S1[1]*S1[1]/Mt)/denom + 1e-5;
    A[1][2]=A[2][1]=(S2[4]-S1[1]*S1[2]/Mt)/denom;
    A[2][2]=(S2[5]-S1[2]*S1[2]/Mt)/denom + 1e-5;
    double V[3][3]={{1,0,0},{0,1,0},{0,0,1}};
    for (int sweep = 0; sweep < 30; ++sweep){
      double offd = fabs(A[0][1])+fabs(A[0][2])+fabs(A[1][2]);
      if (offd < 1e-15) break;
      for (int pi = 0; pi < 3; ++pi) for (int qi = pi+1; qi < 3; ++qi){
        double apq = A[pi][qi];
        if (fabs(apq) < 1e-18) continue;
        double app = A[pi][pi], aqq = A[qi][qi];
        double theta = (aqq - app)/(2.0*apq);
        double t = ((theta >= 0) ? 1.0 : -1.0)/(fabs(theta) + sqrt(theta*theta + 1.0));
        double cth = 1.0/sqrt(t*t + 1.0), sth = t*cth;
        for (int r_ = 0; r_ < 3; ++r_){
          double arp=A[r_][pi], arq=A[r_][qi];
          A[r_][pi]=cth*arp - sth*arq;
          A[r_][qi]=sth*arp + cth*arq;
        }
        for (int c_ = 0; c_ < 3; ++c_){
          double apc=A[pi][c_], aqc=A[qi][c_];
          A[pi][c_]=cth*apc - sth*aqc;
          A[qi][c_]=sth*apc + cth*aqc;
        }
        for (int r_ = 0; r_ < 3; ++r_){
          double vrp=V[r_][pi], vrq=V[r_][qi];
          V[r_][pi]=cth*vrp - sth*vrq;
          V[r_][qi]=sth*vrp + cth*vrq;
        }
      }
    }
    double wv[3] = {A[0][0], A[1][1], A[2][2]};
    for (int j = 0; j < 3; ++j) if (wv[j] < 1e-5) wv[j] = 1e-5;
    double is[3] = {1.0/sqrt(wv[0]), 1.0/sqrt(wv[1]), 1.0/sqrt(wv[2])};
    for (int i = 0; i < 3; ++i)
      for (int j = 0; j < 3; ++j){
        double wz = V[i][0]*is[0]*V[j][0] + V[i][1]*is[1]*V[j][1] + V[i][2]*is[2]*V[j][2];
        zca[b*12 + i*3 + j] = (float)wz;
      }
    for (int j = 0; j < 3; ++j) zca[b*12 + 9 + j] = (float)(S1[j]/Mt);
  }
}

// ---------------- K7: whiten + gamma (nf (b,v,o,m) -> out (b,o,v,m)) ----------------
__global__ __launch_bounds__(256) void k_out(const float* __restrict__ nf,
                                             const float* __restrict__ zca,
                                             const float* __restrict__ gamma,
                                             float* __restrict__ out){
  int i = blockIdx.x*256 + threadIdx.x;   // B*O*M
  if (i >= B*O*M) return;
  int m = i & 2047;
  int bo = i >> 11;
  int o = bo & 63;
  int b = bo >> 6;
  const float* W  = zca + b*12;
  const float* mn = W + 9;
  size_t planeO = (size_t)O*M;
  float c0 = fsub(nf[((size_t)(b*3+0))*planeO + (size_t)o*M + m], mn[0]);
  float c1 = fsub(nf[((size_t)(b*3+1))*planeO + (size_t)o*M + m], mn[1]);
  float c2 = fsub(nf[((size_t)(b*3+2))*planeO + (size_t)o*M + m], mn[2]);
  float g = gamma[o];
  #pragma unroll
  for (int v = 0; v < 3; ++v){
    float val = fadd(fadd(fmul(W[v*3+0], c0), fmul(W[v*3+1], c1)), fmul(W[v*3+2], c2));
    out[(size_t)bo*3*M + (size_t)v*M + m] = fmul(val, g);
  }
}

extern "C" void kernel_launch(void* const* d_in, const int* in_sizes, int n_in,
                              void* d_out, int out_size, void* d_ws, size_t ws_size,
                              hipStream_t stream){
  const float* xyz  = (const float*)d_in[0];
  const float* feat = (const float*)d_in[1];
  const float* Wf   = (const float*)d_in[2];
  const float* Wd   = (const float*)d_in[3];
  const float* bnw  = (const float*)d_in[4];
  const float* bnb  = (const float*)d_in[5];
  const float* gam  = (const float*)d_in[6];
  float* out      = (float*)d_out;
  float* newxyz   = out;              // (B,M,3)
  float* conv_out = out + (size_t)B*M*3;

  char* ws = (char*)d_ws;
  size_t off = 0;
  auto alloc = [&](size_t bytes)->void*{
    void* p = ws + off;
    off = (off + bytes + 255) & ~(size_t)255;
    return p;
  };
  float* featT    = (float*)alloc((size_t)B*N*96*4);
  float* xsoa     = (float*)alloc((size_t)B*3*N*4);
  float* sx       = (float*)alloc((size_t)B*N*4);
  int*   fpsi     = (int*)  alloc((size_t)B*M*4);
  int*   gidx     = (int*)  alloc((size_t)B*M*KNN*4);
  float* bn_part  = (float*)alloc((size_t)B*M*128*4);
  float* bn_stats = (float*)alloc(128*4);
  float* nf       = (float*)alloc((size_t)B*O*3*M*4);
  float* zca      = (float*)alloc(B*12*4);
  float* slx      = (float*)alloc((size_t)B*N*4);
  float* sly      = (float*)alloc((size_t)B*N*4);
  float* slz      = (float*)alloc((size_t)B*N*4);
  unsigned short* sidx = (unsigned short*)alloc((size_t)B*N*2);
  float4* gstat   = (float4*)alloc((size_t)B*NG*16);

  hipLaunchKernelGGL(k_transpose, dim3(B*(N/64)), dim3(256), 0, stream, feat, featT);
  hipLaunchKernelGGL(k_xyz_pre,   dim3(B*N/256),  dim3(256), 0, stream, xyz, xsoa, sx);
  hipLaunchKernelGGL(k_sort,      dim3(B),        dim3(256), 0, stream, xsoa, slx, sly, slz, sidx);
  hipLaunchKernelGGL(k_gstat,     dim3(B*NG),     dim3(64),  0, stream, slx, sly, slz, gstat);
  hipLaunchKernelGGL(k_fps,       dim3(B),        dim3(256), 0, stream,
                     xsoa, slx, sly, slz, sidx, gstat, fpsi, newxyz);
  hipLaunchKernelGGL(k_knn,       dim3(B*M/4),    dim3(256), 0, stream, xsoa, sx, newxyz, gidx);
  hipLaunchKernelGGL((k_conv<0>), dim3(B*M),      dim3(256), 0, stream,
                     featT, xsoa, newxyz, fpsi, gidx, Wf, Wd, bn_stats, bnb, bn_part, nf);
  hipLaunchKernelGGL(k_bnstats,   dim3(O),        dim3(256), 0, stream, bn_part, bnw, bn_stats);
  hipLaunchKernelGGL((k_conv<1>), dim3(B*M),      dim3(256), 0, stream,
                     featT, xsoa, newxyz, fpsi, gidx, Wf, Wd, bn_stats, bnb, bn_part, nf);
  hipLaunchKernelGGL(k_zca,       dim3(B),        dim3(1024),0, stream, nf, zca);
  hipLaunchKernelGGL(k_out,       dim3((B*O*M)/256), dim3(256), 0, stream, nf, zca, gam, conv_out);
}